// Round 2
// baseline (118.188 us; speedup 1.0000x reference)
//
#include <hip/hip_runtime.h>
#include <math.h>

#define S_LEN  2048
#define D_HEAD 128
#define QBLK   64
#define KVBLK  64
#define NWAVES 4
#define BATCH  16

typedef __attribute__((ext_vector_type(4))) float f32x4;
typedef __attribute__((ext_vector_type(8))) short short8;

__device__ __forceinline__ unsigned short f2bf(float x) {
    union { float f; unsigned u; } v; v.f = x;
    unsigned r = v.u + 0x7fffu + ((v.u >> 16) & 1u);
    return (unsigned short)(r >> 16);
}
__device__ __forceinline__ unsigned pack2(unsigned short a, unsigned short b) {
    return (unsigned)a | ((unsigned)b << 16);
}

// One-shot prep: K fp32 -> bf16 (same layout), V fp32 -> V^T bf16 [b][d][k].
__global__ __launch_bounds__(256) void prep(const float* __restrict__ Kg,
                                            const float* __restrict__ Vg,
                                            unsigned short* __restrict__ Kb,
                                            unsigned short* __restrict__ Vt)
{
    const int tid = threadIdx.x;
    const int bid = blockIdx.x;
    if (bid < 2048) {                       // K convert: 16*2048*128 / (256*8) = 2048 blocks
        size_t idx = ((size_t)bid * 256 + tid) * 8;
        float4 a = *(const float4*)(Kg + idx);
        float4 c = *(const float4*)(Kg + idx + 4);
        uint4 u = { pack2(f2bf(a.x),f2bf(a.y)), pack2(f2bf(a.z),f2bf(a.w)),
                    pack2(f2bf(c.x),f2bf(c.y)), pack2(f2bf(c.z),f2bf(c.w)) };
        *(uint4*)(Kb + idx) = u;
    } else {                                // V transpose: 16 batches * 32 ktiles * 2 dtiles (64x64)
        __shared__ unsigned short T[64][65];
        const int tb = bid - 2048;
        const int b = tb >> 6, rem = tb & 63, kt = rem >> 1, dt = rem & 1;
        const size_t base = (size_t)b * S_LEN * D_HEAD;
        {
            const int r = tid >> 2, cf = (tid & 3) * 16;
            const float* vp = Vg + base + (size_t)(kt * 64 + r) * D_HEAD + dt * 64 + cf;
            #pragma unroll
            for (int i = 0; i < 4; ++i) {
                float4 x = *(const float4*)(vp + i * 4);
                T[r][cf + i*4 + 0] = f2bf(x.x);
                T[r][cf + i*4 + 1] = f2bf(x.y);
                T[r][cf + i*4 + 2] = f2bf(x.z);
                T[r][cf + i*4 + 3] = f2bf(x.w);
            }
        }
        __syncthreads();
        {
            const int d = tid >> 2, kc = (tid & 3) * 16;
            unsigned short h[16];
            #pragma unroll
            for (int j = 0; j < 16; ++j) h[j] = T[kc + j][d];
            uint4 u0 = { pack2(h[0],h[1]),  pack2(h[2],h[3]),  pack2(h[4],h[5]),  pack2(h[6],h[7]) };
            uint4 u1 = { pack2(h[8],h[9]),  pack2(h[10],h[11]),pack2(h[12],h[13]),pack2(h[14],h[15]) };
            unsigned short* op = Vt + base + (size_t)(dt * 64 + d) * S_LEN + kt * 64 + kc;
            *(uint4*)(op)     = u0;
            *(uint4*)(op + 8) = u1;
        }
    }
}

template<bool PRE>
__global__ __launch_bounds__(256, 2)
void attn_fwd(const float* __restrict__ Qg, const float* __restrict__ Kf,
              const float* __restrict__ Vf, const unsigned short* __restrict__ Kb,
              const unsigned short* __restrict__ Vt, float* __restrict__ Og)
{
    constexpr float CSC = 0.12751744f;     // log2(e)/sqrt(128), folded into Q
    const int tid  = threadIdx.x;
    const int lane = tid & 63;
    const int w    = tid >> 6;
    const int bid  = blockIdx.x;
    const int b    = bid & 15;
    const int rank = bid >> 4;             // 0..31
    // Complementary pairing: bids c and c+256 land on the same CU (round-robin
    // over 8 XCDs x 32 CUs); their work sums to a uniform 33 tiles.
    const int qb   = (rank < 16) ? (31 - rank) : (rank - 16);
    const int q0   = qb * QBLK;
    const int q0w  = q0 + w * 16;
    const int qc   = lane & 15;
    const int g    = lane >> 4;

    __shared__ __align__(16) unsigned short Klds[2][KVBLK * D_HEAD];  // [k][d] swizzled
    __shared__ __align__(16) unsigned short Vlds[2][D_HEAD * KVBLK];  // V^T [d][k] swizzled
    __shared__ __align__(16) unsigned short Plds[NWAVES][16 * KVBLK]; // per-wave P

    const size_t base = (size_t)b * S_LEN * D_HEAD;

    // ---- Q fragments (MFMA B operand), once per block, scaled ----
    short8 qf[4];
    {
        const float* qp = Qg + base + (size_t)(q0w + qc) * D_HEAD + g * 8;
        #pragma unroll
        for (int db = 0; db < 4; ++db) {
            float4 x0 = *(const float4*)(qp + db * 32);
            float4 x1 = *(const float4*)(qp + db * 32 + 4);
            float t[8] = {x0.x, x0.y, x0.z, x0.w, x1.x, x1.y, x1.z, x1.w};
            short8 f;
            #pragma unroll
            for (int j = 0; j < 8; ++j) f[j] = (short)f2bf(t[j] * CSC);
            qf[db] = f;
        }
    }

    // ---- staging maps ----
    const int krow = tid >> 2, kc8 = (tid & 3) * 8;    // PRE K: 4 x 16B per row
    const int vdp  = tid >> 3, vk8 = (tid & 7) * 8;    // PRE V: d = vdp + i*32
    const int kcb  = (tid & 3) * 32;                   // !PRE K col base
    const int vd   = tid >> 1, vk0 = (tid & 1) * 32;   // !PRE V map

    uint4 kst[4], vst[4];      // PRE staging regs
    float kfl[32], vfl[32];    // !PRE staging regs (unused if PRE)

    auto load_tile = [&](int kv0) {
        if constexpr (PRE) {
            const unsigned short* kp = Kb + base + (size_t)(kv0 + krow) * D_HEAD + kc8;
            #pragma unroll
            for (int i = 0; i < 4; ++i) kst[i] = *(const uint4*)(kp + i * 32);
            const unsigned short* vp = Vt + base + (size_t)vdp * S_LEN + kv0 + vk8;
            #pragma unroll
            for (int i = 0; i < 4; ++i) vst[i] = *(const uint4*)(vp + (size_t)i * 32 * S_LEN);
        } else {
            const float* kp = Kf + base + (size_t)(kv0 + krow) * D_HEAD + kcb;
            #pragma unroll
            for (int i = 0; i < 8; ++i) {
                float4 t = *(const float4*)(kp + i * 4);
                kfl[4*i+0]=t.x; kfl[4*i+1]=t.y; kfl[4*i+2]=t.z; kfl[4*i+3]=t.w;
            }
            const float* vp = Vf + base + (size_t)(kv0 + vk0) * D_HEAD + vd;
            #pragma unroll
            for (int j = 0; j < 32; ++j) vfl[j] = vp[(size_t)j * D_HEAD];
        }
    };

    auto store_tile = [&](int dst) {
        if constexpr (PRE) {
            const int kswz = (krow & 7) << 3;
            #pragma unroll
            for (int i = 0; i < 4; ++i)
                *(uint4*)&Klds[dst][(krow * 128 + kc8 + i * 32) ^ kswz] = kst[i];
            const int vswz = (vdp & 7) << 3;
            #pragma unroll
            for (int i = 0; i < 4; ++i)
                *(uint4*)&Vlds[dst][((vdp + i * 32) * 64 + vk8) ^ vswz] = vst[i];
        } else {
            const int kswz = (krow & 7) << 3;
            #pragma unroll
            for (int i = 0; i < 4; ++i) {
                uint4 u = { pack2(f2bf(kfl[i*8+0]),f2bf(kfl[i*8+1])), pack2(f2bf(kfl[i*8+2]),f2bf(kfl[i*8+3])),
                            pack2(f2bf(kfl[i*8+4]),f2bf(kfl[i*8+5])), pack2(f2bf(kfl[i*8+6]),f2bf(kfl[i*8+7])) };
                *(uint4*)&Klds[dst][(krow * 128 + kcb + i * 8) ^ kswz] = u;
            }
            const int vswz = (vd & 7) << 3;
            #pragma unroll
            for (int i = 0; i < 4; ++i) {
                uint4 u = { pack2(f2bf(vfl[i*8+0]),f2bf(vfl[i*8+1])), pack2(f2bf(vfl[i*8+2]),f2bf(vfl[i*8+3])),
                            pack2(f2bf(vfl[i*8+4]),f2bf(vfl[i*8+5])), pack2(f2bf(vfl[i*8+6]),f2bf(vfl[i*8+7])) };
                *(uint4*)&Vlds[dst][(vd * 64 + vk0 + i * 8) ^ vswz] = u;
            }
        }
    };

    // ---- online softmax state: this lane's q-row is q0w + qc ----
    f32x4 o[8] = {};                       // o[db][r] = O[q=4g+r][d=db*16+qc]
    float m = -1e30f, lsum = 0.f;
    const int qidx = q0w + qc;
    const int n_tiles = q0 / KVBLK + 1;

    load_tile(0);
    store_tile(0);
    __syncthreads();

    for (int t = 0; t < n_tiles; ++t) {
        const int buf = t & 1;
        const int kv0 = t * KVBLK;
        if (t + 1 < n_tiles) load_tile(kv0 + KVBLK);   // issue-early (T14)

        // ---- swapped QK^T: rows = k, cols = q ----
        f32x4 st[4] = {};
        #pragma unroll
        for (int t16 = 0; t16 < 4; ++t16) {
            const int kr = t16 * 16 + qc;
            const int swz = (kr & 7) << 3;
            #pragma unroll
            for (int db = 0; db < 4; ++db) {
                short8 kf = *(const short8*)&Klds[buf][(kr * 128 + db * 32 + g * 8) ^ swz];
                st[t16] = __builtin_amdgcn_mfma_f32_16x16x32_bf16(kf, qf[db], st[t16], 0, 0, 0);
            }
        }
        float s[16];
        #pragma unroll
        for (int t16 = 0; t16 < 4; ++t16)
            #pragma unroll
            for (int r = 0; r < 4; ++r) s[t16*4+r] = st[t16][r];

        if (kv0 + KVBLK - 1 > q0w) {       // diagonal tile: causal mask
            #pragma unroll
            for (int t16 = 0; t16 < 4; ++t16)
                #pragma unroll
                for (int r = 0; r < 4; ++r)
                    if (kv0 + t16 * 16 + g * 4 + r > qidx) s[t16*4+r] = -1e30f;
        }

        // ---- online softmax (row q = qc; reduce over regs + lane groups) ----
        float mx = s[0];
        #pragma unroll
        for (int i = 1; i < 16; ++i) mx = fmaxf(mx, s[i]);
        mx = fmaxf(mx, __shfl_xor(mx, 16));
        mx = fmaxf(mx, __shfl_xor(mx, 32));
        float mnew = fmaxf(m, mx);
        float alpha = exp2f(m - mnew);
        m = mnew;

        float p[16], rs = 0.f;
        #pragma unroll
        for (int i = 0; i < 16; ++i) { p[i] = exp2f(s[i] - mnew); rs += p[i]; }
        rs += __shfl_xor(rs, 16);
        rs += __shfl_xor(rs, 32);
        lsum = lsum * alpha + rs;

        float a_o[4];
        #pragma unroll
        for (int r = 0; r < 4; ++r) a_o[r] = __shfl(alpha, g * 4 + r);
        #pragma unroll
        for (int db = 0; db < 8; ++db)
            #pragma unroll
            for (int r = 0; r < 4; ++r) o[db][r] *= a_o[r];

        // ---- P -> wave-private LDS (bf16): P[q=qc][k = t16*16 + 4g + r] ----
        const int pswz = (qc & 7) << 3;
        #pragma unroll
        for (int t16 = 0; t16 < 4; ++t16) {
            uint2 u = { pack2(f2bf(p[t16*4+0]), f2bf(p[t16*4+1])),
                        pack2(f2bf(p[t16*4+2]), f2bf(p[t16*4+3])) };
            *(uint2*)&Plds[w][(qc * 64 + t16 * 16 + g * 4) ^ pswz] = u;
        }

        // ---- PV: A = P (wave-private, in-wave ds order), B = V^T ----
        #pragma unroll
        for (int ks = 0; ks < 2; ++ks) {
            short8 pa = *(const short8*)&Plds[w][(qc * 64 + ks * 32 + g * 8) ^ pswz];
            #pragma unroll
            for (int db = 0; db < 8; ++db) {
                const int d = db * 16 + qc;
                short8 vf = *(const short8*)&Vlds[buf][(d * 64 + ks * 32 + g * 8) ^ ((d & 7) << 3)];
                o[db] = __builtin_amdgcn_mfma_f32_16x16x32_bf16(pa, vf, o[db], 0, 0, 0);
            }
        }

        if (t + 1 < n_tiles) store_tile(buf ^ 1);  // write-late; one barrier/iter
        __syncthreads();
    }

    // ---- epilogue ----
    float linv = 1.0f / lsum;
    float li[4];
    #pragma unroll
    for (int r = 0; r < 4; ++r) li[r] = __shfl(linv, g * 4 + r);
    #pragma unroll
    for (int db = 0; db < 8; ++db)
        #pragma unroll
        for (int r = 0; r < 4; ++r)
            Og[base + (size_t)(q0w + g * 4 + r) * D_HEAD + db * 16 + qc] = o[db][r] * li[r];
}

extern "C" void kernel_launch(void* const* d_in, const int* in_sizes, int n_in,
                              void* d_out, int out_size, void* d_ws, size_t ws_size,
                              hipStream_t stream) {
    const float* Q = (const float*)d_in[0];
    const float* K = (const float*)d_in[1];
    const float* V = (const float*)d_in[2];
    float* O = (float*)d_out;
    const size_t elems = (size_t)BATCH * S_LEN * D_HEAD;
    const size_t need  = 2 * elems * sizeof(unsigned short);
    if (ws_size >= need) {
        unsigned short* Kb = (unsigned short*)d_ws;
        unsigned short* Vt = Kb + elems;
        prep<<<dim3(2048 + BATCH * 32 * 2), dim3(256), 0, stream>>>(K, V, Kb, Vt);
        attn_fwd<true><<<dim3(512), dim3(256), 0, stream>>>(Q, K, V, Kb, Vt, O);
    } else {
        attn_fwd<false><<<dim3(512), dim3(256), 0, stream>>>(Q, K, V, nullptr, nullptr, O);
    }
}

// Round 3
// 75.063 us; speedup vs baseline: 1.5745x; 1.5745x over previous
//
#include <hip/hip_runtime.h>
#include <math.h>

#define S_LEN  2048
#define D_HEAD 128
#define QBLK   64
#define KVBLK  64
#define NWAVES 4
#define BATCH  16
#define NKVT   (S_LEN / KVBLK)     // 32 kv tiles per batch
#define TILE_SH 8192               // shorts per 64x128 tile image (16 KB)

typedef __attribute__((ext_vector_type(4))) float f32x4;
typedef __attribute__((ext_vector_type(8))) short short8;

__device__ __forceinline__ unsigned short f2bf(float x) {
    union { float f; unsigned u; } v; v.f = x;
    unsigned r = v.u + 0x7fffu + ((v.u >> 16) & 1u);
    return (unsigned short)(r >> 16);
}
__device__ __forceinline__ unsigned pack2(unsigned short a, unsigned short b) {
    return (unsigned)a | ((unsigned)b << 16);
}
__device__ __forceinline__ unsigned cvtpk(float lo, float hi) {   // 2xf32 -> packed bf16
    unsigned r;
    asm("v_cvt_pk_bf16_f32 %0, %1, %2" : "=v"(r) : "v"(lo), "v"(hi));
    return r;
}
__device__ __forceinline__ void gld16(const void* g, void* l) {   // 16B global->LDS DMA
    __builtin_amdgcn_global_load_lds(
        (const __attribute__((address_space(1))) void*)g,
        (__attribute__((address_space(3))) void*)l, 16, 0, 0);
}

// prep: one block per (batch, kv-tile). Emits PRE-SWIZZLED contiguous LDS images:
//   K image: img[(k*128 + d) ^ ((k&7)<<3)] = bf16(K[kv0+k][d])
//   V image: img[(d*64 + kk) ^ ((d&7)<<3)] = bf16(V[kv0+kk][d])   (V transposed)
// attn then DMAs images linearly (global_load_lds) and reads with the same XOR.
__global__ __launch_bounds__(256) void prep(const float* __restrict__ K,
                                            const float* __restrict__ V,
                                            unsigned short* __restrict__ Kp,
                                            unsigned short* __restrict__ Vp)
{
    const int tid = threadIdx.x;
    const int bid = blockIdx.x;             // b*NKVT + t
    const int b = bid >> 5, t = bid & 31;
    const size_t ibase = (size_t)b * S_LEN * D_HEAD + (size_t)t * KVBLK * D_HEAD;
    unsigned short* ko = Kp + (size_t)bid * TILE_SH;
    unsigned short* vo = Vp + (size_t)bid * TILE_SH;

    #pragma unroll
    for (int c = 0; c < 4; ++c) {           // K image: 1024 chunks of 8 shorts
        int i  = c * 256 + tid;
        int k  = i >> 4;
        int d8 = ((i & 15) * 8) ^ ((k & 7) << 3);
        const float* sp = K + ibase + (size_t)k * D_HEAD + d8;
        float4 a = *(const float4*)sp;
        float4 bb = *(const float4*)(sp + 4);
        uint4 u = { pack2(f2bf(a.x),f2bf(a.y)),  pack2(f2bf(a.z),f2bf(a.w)),
                    pack2(f2bf(bb.x),f2bf(bb.y)),pack2(f2bf(bb.z),f2bf(bb.w)) };
        *(uint4*)(ko + i * 8) = u;
    }

    __shared__ unsigned short Vb[KVBLK][D_HEAD + 2];
    {
        const int r  = tid >> 2;
        const int c0 = (tid & 3) * 32;
        const float* sp = V + ibase + (size_t)r * D_HEAD + c0;
        #pragma unroll
        for (int i = 0; i < 8; ++i) {
            float4 x = *(const float4*)(sp + i * 4);
            Vb[r][c0+i*4+0] = f2bf(x.x); Vb[r][c0+i*4+1] = f2bf(x.y);
            Vb[r][c0+i*4+2] = f2bf(x.z); Vb[r][c0+i*4+3] = f2bf(x.w);
        }
    }
    __syncthreads();
    #pragma unroll
    for (int c = 0; c < 4; ++c) {           // V image
        int i   = c * 256 + tid;
        int d   = i >> 3;
        int kk0 = ((i & 7) * 8) ^ ((d & 7) << 3);
        unsigned short h[8];
        #pragma unroll
        for (int j = 0; j < 8; ++j) h[j] = Vb[kk0 + j][d];
        uint4 u = { pack2(h[0],h[1]), pack2(h[2],h[3]), pack2(h[4],h[5]), pack2(h[6],h[7]) };
        *(uint4*)(vo + i * 8) = u;
    }
}

__global__ __launch_bounds__(256, 2)
void attn_fwd(const float* __restrict__ Qg, const unsigned short* __restrict__ Kp,
              const unsigned short* __restrict__ Vp, float* __restrict__ Og)
{
    constexpr float CSC = 0.12751744f;      // log2(e)/sqrt(128), folded into Q
    const int tid  = threadIdx.x;
    const int lane = tid & 63;
    const int w    = tid >> 6;
    const int bid  = blockIdx.x;
    const int b    = bid & 15;
    const int rank = bid >> 4;
    const int qb   = (rank < 16) ? (31 - rank) : (rank - 16);  // complementary pairing
    const int q0   = qb * QBLK;
    const int q0w  = q0 + w * 16;
    const int qc   = lane & 15;
    const int g    = lane >> 4;

    __shared__ __align__(16) unsigned short Klds[2][TILE_SH];
    __shared__ __align__(16) unsigned short Vlds[2][TILE_SH];
    __shared__ __align__(16) unsigned short Plds[NWAVES][16 * KVBLK];

    const size_t base = (size_t)b * S_LEN * D_HEAD;

    // ---- Q fragments (MFMA B operand), pre-scaled ----
    short8 qf[4];
    {
        const float* qp = Qg + base + (size_t)(q0w + qc) * D_HEAD + g * 8;
        #pragma unroll
        for (int db = 0; db < 4; ++db) {
            float4 x0 = *(const float4*)(qp + db * 32);
            float4 x1 = *(const float4*)(qp + db * 32 + 4);
            float tt[8] = {x0.x, x0.y, x0.z, x0.w, x1.x, x1.y, x1.z, x1.w};
            short8 f;
            #pragma unroll
            for (int j = 0; j < 8; ++j) f[j] = (short)f2bf(tt[j] * CSC);
            qf[db] = f;
        }
    }

    // ---- DMA staging: zero registers, zero VALU ----
    const int tb = b * NKVT;
    auto stage = [&](int t, int dst) {
        const unsigned short* ks = Kp + (size_t)(tb + t) * TILE_SH + w * 2048 + lane * 8;
        const unsigned short* vs = Vp + (size_t)(tb + t) * TILE_SH + w * 2048 + lane * 8;
        unsigned short* kd = &Klds[dst][w * 2048];
        unsigned short* vd = &Vlds[dst][w * 2048];
        #pragma unroll
        for (int i = 0; i < 4; ++i) {
            gld16(ks + i * 512, kd + i * 512);
            gld16(vs + i * 512, vd + i * 512);
        }
    };

    f32x4 o[8] = {};                        // o[db][r] = O[q=4g+r][d=db*16+qc]
    float m = -1e30f, lsum = 0.f;
    const int qidx = q0w + qc;
    const int n_tiles = qb + 1;

    stage(0, 0);
    __syncthreads();

    for (int t = 0; t < n_tiles; ++t) {
        const int buf = t & 1;
        const int kv0 = t * KVBLK;
        if (t + 1 < n_tiles) stage(t + 1, buf ^ 1);   // async DMA into free buffer

        // On the diagonal tile, subtiles with t16 > w are fully masked for this wave.
        const int t16max = (t == n_tiles - 1) ? w : 3;

        // ---- swapped QK^T: rows = k, cols = q ----
        f32x4 st[4] = {};
        __builtin_amdgcn_s_setprio(1);
        #pragma unroll
        for (int t16 = 0; t16 < 4; ++t16) {
            if (t16 <= t16max) {
                const int kr = t16 * 16 + qc;
                const int swz = (kr & 7) << 3;
                #pragma unroll
                for (int db = 0; db < 4; ++db) {
                    short8 kf = *(const short8*)&Klds[buf][(kr * 128 + db * 32 + g * 8) ^ swz];
                    st[t16] = __builtin_amdgcn_mfma_f32_16x16x32_bf16(kf, qf[db], st[t16], 0, 0, 0);
                }
            }
        }
        __builtin_amdgcn_s_setprio(0);

        float s[16];
        #pragma unroll
        for (int t16 = 0; t16 < 4; ++t16)
            #pragma unroll
            for (int r = 0; r < 4; ++r)
                s[t16*4+r] = (t16 <= t16max) ? st[t16][r] : -1e30f;

        if (kv0 + KVBLK - 1 > q0w) {        // diagonal: per-lane causal mask
            #pragma unroll
            for (int t16 = 0; t16 < 4; ++t16)
                #pragma unroll
                for (int r = 0; r < 4; ++r)
                    if (kv0 + t16 * 16 + g * 4 + r > qidx) s[t16*4+r] = -1e30f;
        }

        // ---- online softmax with defer-max (T13, THR=8 in log2 domain) ----
        float m0 = fmaxf(fmaxf(s[0],s[1]), fmaxf(s[2],s[3]));
        float m1 = fmaxf(fmaxf(s[4],s[5]), fmaxf(s[6],s[7]));
        float m2 = fmaxf(fmaxf(s[8],s[9]), fmaxf(s[10],s[11]));
        float m3 = fmaxf(fmaxf(s[12],s[13]), fmaxf(s[14],s[15]));
        float mx = fmaxf(fmaxf(m0,m1), fmaxf(m2,m3));
        mx = fmaxf(mx, __shfl_xor(mx, 16));
        mx = fmaxf(mx, __shfl_xor(mx, 32));

        if (__any(mx > m + 8.0f)) {         // rescale only when max grew materially
            float mnew = fmaxf(m, mx);
            float alpha = exp2f(m - mnew);
            m = mnew;
            lsum *= alpha;
            float a_o[4];
            #pragma unroll
            for (int r = 0; r < 4; ++r) a_o[r] = __shfl(alpha, g * 4 + r);
            #pragma unroll
            for (int db = 0; db < 8; ++db)
                #pragma unroll
                for (int r = 0; r < 4; ++r) o[db][r] *= a_o[r];
        }

        float p[16];
        #pragma unroll
        for (int i = 0; i < 16; ++i) p[i] = exp2f(s[i] - m);
        float r0 = (p[0]+p[1]) + (p[2]+p[3]);
        float r1 = (p[4]+p[5]) + (p[6]+p[7]);
        float r2 = (p[8]+p[9]) + (p[10]+p[11]);
        float r3 = (p[12]+p[13]) + (p[14]+p[15]);
        float rs = (r0+r1) + (r2+r3);
        rs += __shfl_xor(rs, 16);
        rs += __shfl_xor(rs, 32);
        lsum += rs;

        // ---- P -> wave-private LDS (bf16, swizzled) ----
        const int pswz = (qc & 7) << 3;
        #pragma unroll
        for (int t16 = 0; t16 < 4; ++t16) {
            uint2 u = { cvtpk(p[t16*4+0], p[t16*4+1]), cvtpk(p[t16*4+2], p[t16*4+3]) };
            *(uint2*)&Plds[w][(qc * 64 + t16 * 16 + g * 4) ^ pswz] = u;
        }

        // ---- PV ----
        __builtin_amdgcn_s_setprio(1);
        #pragma unroll
        for (int ks = 0; ks < 2; ++ks) {
            short8 pa = *(const short8*)&Plds[w][(qc * 64 + ks * 32 + g * 8) ^ pswz];
            #pragma unroll
            for (int db = 0; db < 8; ++db) {
                const int d = db * 16 + qc;
                short8 vf = *(const short8*)&Vlds[buf][(d * 64 + ks * 32 + g * 8) ^ ((d & 7) << 3)];
                o[db] = __builtin_amdgcn_mfma_f32_16x16x32_bf16(pa, vf, o[db], 0, 0, 0);
            }
        }
        __builtin_amdgcn_s_setprio(0);

        __syncthreads();   // drains DMA (next tile staged) + protects buffer reuse
    }

    // ---- epilogue ----
    float linv = 1.0f / lsum;
    float li[4];
    #pragma unroll
    for (int r = 0; r < 4; ++r) li[r] = __shfl(linv, g * 4 + r);
    #pragma unroll
    for (int db = 0; db < 8; ++db)
        #pragma unroll
        for (int r = 0; r < 4; ++r)
            Og[base + (size_t)(q0w + g * 4 + r) * D_HEAD + db * 16 + qc] = o[db][r] * li[r];
}

extern "C" void kernel_launch(void* const* d_in, const int* in_sizes, int n_in,
                              void* d_out, int out_size, void* d_ws, size_t ws_size,
                              hipStream_t stream) {
    const float* Q = (const float*)d_in[0];
    const float* K = (const float*)d_in[1];
    const float* V = (const float*)d_in[2];
    float* O = (float*)d_out;
    unsigned short* Kp = (unsigned short*)d_ws;                      // 8.4 MB
    unsigned short* Vp = Kp + (size_t)BATCH * NKVT * TILE_SH;        // 8.4 MB
    prep<<<dim3(BATCH * NKVT), dim3(256), 0, stream>>>(K, V, Kp, Vp);
    attn_fwd<<<dim3(512), dim3(256), 0, stream>>>(Q, Kp, Vp, O);
}